// Round 1
// baseline (645.235 us; speedup 1.0000x reference)
//
#include <hip/hip_runtime.h>
#include <math.h>

// MultiHeadDotAttn: B=64, S=2048, QD=1024, KD=512, AD=512, H=8
//
// Algebraic reordering: instead of materializing k[b,h,s,a] (549 GFLOP, 2.1GB),
// precompute qk[b,h,d] = sum_a q[b,h,a]*Wk[h,a,d], then
// energy[b,h,s] = dot(keys[b,s,:], qk[b,h,:])  (1 GFLOP, one pass over keys).
// Masked positions (s >= key_len[b]) give attn == 0 exactly (f32 exp underflow
// in the reference), so we skip reading keys/value there entirely.

#define B_  64
#define S_  2048
#define QD_ 1024
#define KD_ 512
#define AD_ 512
#define H_  8

// ---------------------------------------------------------------------------
// K1: q[b, n] = sum_k query[b,k] * Wq[n,k],  n = h*AD+a  (C = A @ W^T, NT)
// grid (4 m-tiles of 16, 64 n-tiles of 64), block 256
__global__ __launch_bounds__(256) void k1_qproj(const float* __restrict__ query,
                                                const float* __restrict__ Wq,
                                                float* __restrict__ qo) {
    __shared__ float As[16][65];
    __shared__ float Ws[64][65];
    const int t = threadIdx.x;
    const int m0 = blockIdx.x * 16, n0 = blockIdx.y * 64;
    const int nl = t & 63, mb = (t >> 6) * 4;
    float acc[4] = {0.f, 0.f, 0.f, 0.f};
    for (int kc = 0; kc < QD_; kc += 64) {
#pragma unroll
        for (int i = 0; i < 4; ++i) {
            int idx = t + i * 256, r = idx >> 6, c = idx & 63;
            As[r][c] = query[(m0 + r) * QD_ + kc + c];
        }
#pragma unroll
        for (int i = 0; i < 16; ++i) {
            int idx = t + i * 256, r = idx >> 6, c = idx & 63;
            Ws[r][c] = Wq[(size_t)(n0 + r) * QD_ + kc + c];
        }
        __syncthreads();
#pragma unroll
        for (int k = 0; k < 64; ++k) {
            float w = Ws[nl][k];
#pragma unroll
            for (int j = 0; j < 4; ++j) acc[j] += As[mb + j][k] * w;
        }
        __syncthreads();
    }
#pragma unroll
    for (int j = 0; j < 4; ++j)
        qo[(m0 + mb + j) * (H_ * AD_) + n0 + nl] = acc[j];
}

// ---------------------------------------------------------------------------
// K2: qk[b, h*KD+d] = sum_a q[b, h*AD+a] * Wk[h,a,d]   (per-head TN GEMM)
// grid (4 m-tiles, 8 n-tiles, 8 heads), block 256
__global__ __launch_bounds__(256) void k2_qk(const float* __restrict__ q,
                                             const float* __restrict__ Wk,
                                             float* __restrict__ qk) {
    __shared__ float As[16][65];
    __shared__ float Ws[64][65];  // [k][n]
    const int t = threadIdx.x;
    const int m0 = blockIdx.x * 16, n0 = blockIdx.y * 64, h = blockIdx.z;
    const float* Wh = Wk + (size_t)h * AD_ * KD_;
    const int nl = t & 63, mb = (t >> 6) * 4;
    float acc[4] = {0.f, 0.f, 0.f, 0.f};
    for (int ac = 0; ac < AD_; ac += 64) {
#pragma unroll
        for (int i = 0; i < 4; ++i) {
            int idx = t + i * 256, r = idx >> 6, c = idx & 63;
            As[r][c] = q[(m0 + r) * (H_ * AD_) + h * AD_ + ac + c];
        }
#pragma unroll
        for (int i = 0; i < 16; ++i) {
            int idx = t + i * 256, r = idx >> 6, c = idx & 63;  // r = k, c = n
            Ws[r][c] = Wh[(size_t)(ac + r) * KD_ + n0 + c];
        }
        __syncthreads();
#pragma unroll
        for (int k = 0; k < 64; ++k) {
            float w = Ws[k][nl];
#pragma unroll
            for (int j = 0; j < 4; ++j) acc[j] += As[mb + j][k] * w;
        }
        __syncthreads();
    }
#pragma unroll
    for (int j = 0; j < 4; ++j)
        qk[(m0 + mb + j) * (H_ * KD_) + h * KD_ + n0 + nl] = acc[j];
}

// ---------------------------------------------------------------------------
// K3: energy[b,h,s] = dot(keys[b,s,:KD], qk[b,h,:KD])
// wave-per-row; lane holds qk[h][lane*8..+8] in regs (64 VGPRs).
// grid (16 s-chunks of 128, 64 b), block 256 (4 waves, 32 rows each)
__global__ __launch_bounds__(256) void k3_energy(const float* __restrict__ keys,
                                                 const float* __restrict__ qk,
                                                 const int* __restrict__ key_len,
                                                 float* __restrict__ energy) {
    const int b = blockIdx.y;
    const int klen = key_len[b];
    const int s0 = blockIdx.x * 128;
    if (s0 >= klen) return;  // fully masked: energy never read downstream
    const int t = threadIdx.x;
    const int lane = t & 63, w = t >> 6;

    const float4* qk4 = reinterpret_cast<const float4*>(qk + (size_t)b * (H_ * KD_));
    float qkr[8][8];
#pragma unroll
    for (int h = 0; h < H_; ++h) {
        float4 u0 = qk4[h * (KD_ / 4) + lane * 2];
        float4 u1 = qk4[h * (KD_ / 4) + lane * 2 + 1];
        qkr[h][0] = u0.x; qkr[h][1] = u0.y; qkr[h][2] = u0.z; qkr[h][3] = u0.w;
        qkr[h][4] = u1.x; qkr[h][5] = u1.y; qkr[h][6] = u1.z; qkr[h][7] = u1.w;
    }

    const int sbeg = s0 + w * 32;
    for (int i = 0; i < 32; ++i) {
        int s = sbeg + i;
        if (s >= klen) break;  // wave-uniform
        const float4* kp = reinterpret_cast<const float4*>(
            keys + (size_t)(b * S_ + s) * KD_ + lane * 8);
        float4 k0 = kp[0], k1 = kp[1];
        float kf[8] = {k0.x, k0.y, k0.z, k0.w, k1.x, k1.y, k1.z, k1.w};
        float partial[8];
#pragma unroll
        for (int h = 0; h < H_; ++h) {
            float p = 0.f;
#pragma unroll
            for (int j = 0; j < 8; ++j) p += kf[j] * qkr[h][j];
            partial[h] = p;
        }
#pragma unroll
        for (int h = 0; h < H_; ++h) {
#pragma unroll
            for (int off = 32; off >= 1; off >>= 1)
                partial[h] += __shfl_xor(partial[h], off, 64);
        }
#pragma unroll
        for (int h = 0; h < H_; ++h)
            if (lane == h) energy[((size_t)b * H_ + h) * S_ + s] = partial[h];
    }
}

// ---------------------------------------------------------------------------
// K4: masked softmax over S per (b,h) row; writes attn output.
// Also zero-initializes the contexts region of d_out (poisoned 0xAA) so that
// K5 can accumulate with atomics. grid 512 (= B*H), block 256.
__global__ __launch_bounds__(256) void k4_softmax(const float* __restrict__ energy,
                                                  const int* __restrict__ key_len,
                                                  float* __restrict__ attn,
                                                  float* __restrict__ ctx_zero) {
    const int bh = blockIdx.x;  // b*H + h
    const int b = bh >> 3;
    const int t = threadIdx.x;
    // zero contexts: 512 floats per block covers B*H*KD = 262144
    ctx_zero[bh * 512 + t] = 0.f;
    ctx_zero[bh * 512 + 256 + t] = 0.f;

    const int klen = key_len[b];
    const float* e = energy + (size_t)bh * S_;
    float ev[8];
    float m = -3.0e38f;
#pragma unroll
    for (int j = 0; j < 8; ++j) {
        int s = t + j * 256;
        float x = (s < klen) ? e[s] : -3.0e38f;
        ev[j] = x;
        m = fmaxf(m, x);
    }
#pragma unroll
    for (int off = 32; off >= 1; off >>= 1) m = fmaxf(m, __shfl_xor(m, off, 64));
    __shared__ float redm[4];
    if ((t & 63) == 0) redm[t >> 6] = m;
    __syncthreads();
    m = fmaxf(fmaxf(redm[0], redm[1]), fmaxf(redm[2], redm[3]));

    float sum = 0.f;
#pragma unroll
    for (int j = 0; j < 8; ++j) {
        int s = t + j * 256;
        float p = (s < klen) ? __expf(ev[j] - m) : 0.f;
        ev[j] = p;
        sum += p;
    }
#pragma unroll
    for (int off = 32; off >= 1; off >>= 1) sum += __shfl_xor(sum, off, 64);
    __shared__ float reds[4];
    if ((t & 63) == 0) reds[t >> 6] = sum;
    __syncthreads();
    sum = reds[0] + reds[1] + reds[2] + reds[3];
    const float inv = 1.f / sum;

    float* a = attn + (size_t)bh * S_;
#pragma unroll
    for (int j = 0; j < 8; ++j) a[t + j * 256] = ev[j] * inv;  // masked -> exact 0
}

// ---------------------------------------------------------------------------
// K5: context[b,h,d] += sum_s attn[b,h,s] * value[b,s,d]
// grid (16 s-chunks of 128, 64 b), block 256. float4 value loads, attn tile
// in LDS, f32 atomicAdd accumulation (contexts zeroed by K4).
__global__ __launch_bounds__(256) void k5_context(const float* __restrict__ value,
                                                  const float* __restrict__ attn,
                                                  const int* __restrict__ key_len,
                                                  float* __restrict__ ctx) {
    const int b = blockIdx.y;
    const int klen = key_len[b];
    const int s_base = blockIdx.x * 128;
    if (s_base >= klen) return;  // attn is exactly 0 there
    const int t = threadIdx.x;

    __shared__ float at[8][128];
#pragma unroll
    for (int i = 0; i < 4; ++i) {
        int idx = t + i * 256, h = idx >> 7, si = idx & 127;
        int s = s_base + si;
        at[h][si] = (s < klen) ? attn[((size_t)b * H_ + h) * S_ + s] : 0.f;
    }
    __syncthreads();

    const int tt = t & 127;  // float4 column index
    const int sh = t >> 7;   // s-half 0/1
    const int d = tt * 4;
    const int siBeg = sh * 64;
    const int siEnd = min(siBeg + 64, klen - s_base);

    float4 acc[8];
#pragma unroll
    for (int h = 0; h < H_; ++h) acc[h] = make_float4(0.f, 0.f, 0.f, 0.f);

    for (int si = siBeg; si < siEnd; ++si) {
        const float4 v = *reinterpret_cast<const float4*>(
            value + (size_t)(b * S_ + s_base + si) * KD_ + d);
#pragma unroll
        for (int h = 0; h < H_; ++h) {
            float a = at[h][si];
            acc[h].x += a * v.x; acc[h].y += a * v.y;
            acc[h].z += a * v.z; acc[h].w += a * v.w;
        }
    }

    float* cb = ctx + (size_t)b * (H_ * KD_);
#pragma unroll
    for (int h = 0; h < H_; ++h) {
        atomicAdd(&cb[h * KD_ + d + 0], acc[h].x);
        atomicAdd(&cb[h * KD_ + d + 1], acc[h].y);
        atomicAdd(&cb[h * KD_ + d + 2], acc[h].z);
        atomicAdd(&cb[h * KD_ + d + 3], acc[h].w);
    }
}

// ---------------------------------------------------------------------------
extern "C" void kernel_launch(void* const* d_in, const int* in_sizes, int n_in,
                              void* d_out, int out_size, void* d_ws, size_t ws_size,
                              hipStream_t stream) {
    const float* query   = (const float*)d_in[0];  // (B, QD)
    const float* keys    = (const float*)d_in[1];  // (B, S, KD)
    const float* value   = (const float*)d_in[2];  // (B, S, KD)
    const int*   key_len = (const int*)d_in[3];    // (B,)
    const float* Wq      = (const float*)d_in[4];  // (H, AD, QD)
    const float* Wk      = (const float*)d_in[5];  // (H, AD, KD)

    float* out = (float*)d_out;
    float* ctx_out  = out;                        // (B, H*KD) = 262144 floats
    float* attn_out = out + (size_t)B_ * H_ * KD_; // (B, H, S) = 1048576 floats

    float* ws    = (float*)d_ws;
    float* q_ws  = ws;                                  // B*H*AD   = 262144
    float* qk_ws = ws + (size_t)B_ * H_ * AD_;          // B*H*KD   = 262144
    float* e_ws  = qk_ws + (size_t)B_ * H_ * KD_;       // B*H*S    = 1048576

    hipLaunchKernelGGL(k1_qproj, dim3(4, 64), dim3(256), 0, stream, query, Wq, q_ws);
    hipLaunchKernelGGL(k2_qk, dim3(4, 8, 8), dim3(256), 0, stream, q_ws, Wk, qk_ws);
    hipLaunchKernelGGL(k3_energy, dim3(16, 64), dim3(256), 0, stream,
                       keys, qk_ws, key_len, e_ws);
    hipLaunchKernelGGL(k4_softmax, dim3(512), dim3(256), 0, stream,
                       e_ws, key_len, attn_out, ctx_out);
    hipLaunchKernelGGL(k5_context, dim3(16, 64), dim3(256), 0, stream,
                       value, attn_out, key_len, ctx_out);
}

// Round 3
// 585.244 us; speedup vs baseline: 1.1025x; 1.1025x over previous
//
#include <hip/hip_runtime.h>
#include <math.h>

// MultiHeadDotAttn: B=64, S=2048, QD=1024, KD=512, AD=512, H=8
//
// Algebraic reordering: qk[b,h,d] = sum_a q[b,h,a]*Wk[h,a,d], then
// energy[b,h,s] = dot(keys[b,s,:], qk[b,h,:]). Masked positions (s>=key_len)
// are exact zeros after softmax (f32 underflow), so keys/value reads there
// are skipped entirely.
//
// R2 changes vs R1 (resubmitted unchanged in R3 after infra timeout):
//  - K3: compacted multi-value butterfly (10 shuffles/row vs 48), 64-row
//    s-chunks (2x TLP), full-trip fast path for load pipelining.
//  - K5: no atomics -> per-64-row-chunk partials in ws; new K6 sums only the
//    ceil(klen/64) live chunks per b (never reads poisoned ws).
//  - K4 no longer zero-fills ctx (K6 writes every element).

#define B_  64
#define S_  2048
#define QD_ 1024
#define KD_ 512
#define AD_ 512
#define H_  8

// ---------------------------------------------------------------------------
// K1: q[b, n] = sum_k query[b,k] * Wq[n,k],  n = h*AD+a  (C = A @ W^T, NT)
// grid (4 m-tiles of 16, 64 n-tiles of 64), block 256
__global__ __launch_bounds__(256) void k1_qproj(const float* __restrict__ query,
                                                const float* __restrict__ Wq,
                                                float* __restrict__ qo) {
    __shared__ float As[16][65];
    __shared__ float Ws[64][65];
    const int t = threadIdx.x;
    const int m0 = blockIdx.x * 16, n0 = blockIdx.y * 64;
    const int nl = t & 63, mb = (t >> 6) * 4;
    float acc[4] = {0.f, 0.f, 0.f, 0.f};
    for (int kc = 0; kc < QD_; kc += 64) {
#pragma unroll
        for (int i = 0; i < 4; ++i) {
            int idx = t + i * 256, r = idx >> 6, c = idx & 63;
            As[r][c] = query[(m0 + r) * QD_ + kc + c];
        }
#pragma unroll
        for (int i = 0; i < 16; ++i) {
            int idx = t + i * 256, r = idx >> 6, c = idx & 63;
            Ws[r][c] = Wq[(size_t)(n0 + r) * QD_ + kc + c];
        }
        __syncthreads();
#pragma unroll
        for (int k = 0; k < 64; ++k) {
            float w = Ws[nl][k];
#pragma unroll
            for (int j = 0; j < 4; ++j) acc[j] += As[mb + j][k] * w;
        }
        __syncthreads();
    }
#pragma unroll
    for (int j = 0; j < 4; ++j)
        qo[(m0 + mb + j) * (H_ * AD_) + n0 + nl] = acc[j];
}

// ---------------------------------------------------------------------------
// K2: qk[b, h*KD+d] = sum_a q[b, h*AD+a] * Wk[h,a,d]   (per-head TN GEMM)
// grid (4 m-tiles, 8 n-tiles, 8 heads), block 256
__global__ __launch_bounds__(256) void k2_qk(const float* __restrict__ q,
                                             const float* __restrict__ Wk,
                                             float* __restrict__ qk) {
    __shared__ float As[16][65];
    __shared__ float Ws[64][65];  // [k][n]
    const int t = threadIdx.x;
    const int m0 = blockIdx.x * 16, n0 = blockIdx.y * 64, h = blockIdx.z;
    const float* Wh = Wk + (size_t)h * AD_ * KD_;
    const int nl = t & 63, mb = (t >> 6) * 4;
    float acc[4] = {0.f, 0.f, 0.f, 0.f};
    for (int ac = 0; ac < AD_; ac += 64) {
#pragma unroll
        for (int i = 0; i < 4; ++i) {
            int idx = t + i * 256, r = idx >> 6, c = idx & 63;
            As[r][c] = q[(m0 + r) * (H_ * AD_) + h * AD_ + ac + c];
        }
#pragma unroll
        for (int i = 0; i < 16; ++i) {
            int idx = t + i * 256, r = idx >> 6, c = idx & 63;  // r = k, c = n
            Ws[r][c] = Wh[(size_t)(ac + r) * KD_ + n0 + c];
        }
        __syncthreads();
#pragma unroll
        for (int k = 0; k < 64; ++k) {
            float w = Ws[k][nl];
#pragma unroll
            for (int j = 0; j < 4; ++j) acc[j] += As[mb + j][k] * w;
        }
        __syncthreads();
    }
#pragma unroll
    for (int j = 0; j < 4; ++j)
        qk[(m0 + mb + j) * (H_ * KD_) + h * KD_ + n0 + nl] = acc[j];
}

// ---------------------------------------------------------------------------
// K3: energy[b,h,s] = dot(keys[b,s,:KD], qk[b,h,:KD])
// wave-per-row, lane holds qk[h][lane*8..+8] in regs (64 VGPRs).
// Compacted 8-value butterfly: 10 shuffles/row instead of 48.
// grid (32 s-chunks of 64, 64 b), block 256 (4 waves, 16 rows each)
__global__ __launch_bounds__(256) void k3_energy(const float* __restrict__ keys,
                                                 const float* __restrict__ qk,
                                                 const int* __restrict__ key_len,
                                                 float* __restrict__ energy) {
    const int b = blockIdx.y;
    const int klen = key_len[b];
    const int s0 = blockIdx.x * 64;
    if (s0 >= klen) return;  // fully masked: energy never read downstream
    const int t = threadIdx.x;
    const int lane = t & 63, w = t >> 6;

    const float4* qk4 = reinterpret_cast<const float4*>(qk + (size_t)b * (H_ * KD_));
    float qkr[8][8];
#pragma unroll
    for (int h = 0; h < H_; ++h) {
        float4 u0 = qk4[h * (KD_ / 4) + lane * 2];
        float4 u1 = qk4[h * (KD_ / 4) + lane * 2 + 1];
        qkr[h][0] = u0.x; qkr[h][1] = u0.y; qkr[h][2] = u0.z; qkr[h][3] = u0.w;
        qkr[h][4] = u1.x; qkr[h][5] = u1.y; qkr[h][6] = u1.z; qkr[h][7] = u1.w;
    }

    const int sbeg = s0 + w * 16;
    const int count = min(16, klen - sbeg);
    if (count <= 0) return;

    auto row = [&](int s) {
        const float4* kp = reinterpret_cast<const float4*>(
            keys + (size_t)(b * S_ + s) * KD_ + lane * 8);
        float4 k0 = kp[0], k1 = kp[1];
        float kf[8] = {k0.x, k0.y, k0.z, k0.w, k1.x, k1.y, k1.z, k1.w};
        float p[8];
#pragma unroll
        for (int h = 0; h < 8; ++h) {
            float a = 0.f;
#pragma unroll
            for (int j = 0; j < 8; ++j) a += kf[j] * qkr[h][j];
            p[h] = a;
        }
        // compacted reduction: fold head-count while reducing lanes.
        // after the 3 folding stages lane l (in each group of 8) holds head
        // h = 4*b0 + 2*b1 + b2 summed over its 8-lane group.
#pragma unroll
        for (int j = 0; j < 4; ++j) {
            float keep = (lane & 1) ? p[j + 4] : p[j];
            float send = (lane & 1) ? p[j] : p[j + 4];
            p[j] = keep + __shfl_xor(send, 1, 64);
        }
#pragma unroll
        for (int j = 0; j < 2; ++j) {
            float keep = (lane & 2) ? p[j + 2] : p[j];
            float send = (lane & 2) ? p[j] : p[j + 2];
            p[j] = keep + __shfl_xor(send, 2, 64);
        }
        {
            float keep = (lane & 4) ? p[1] : p[0];
            float send = (lane & 4) ? p[0] : p[1];
            p[0] = keep + __shfl_xor(send, 4, 64);
        }
        p[0] += __shfl_xor(p[0], 8, 64);
        p[0] += __shfl_xor(p[0], 16, 64);
        p[0] += __shfl_xor(p[0], 32, 64);
        if (lane < 8) {
            const int h = ((lane & 1) << 2) | (lane & 2) | ((lane >> 2) & 1);
            energy[((size_t)b * H_ + h) * S_ + s] = p[0];
        }
    };

    if (count == 16) {
#pragma unroll 4
        for (int i = 0; i < 16; ++i) row(sbeg + i);
    } else {
        for (int i = 0; i < count; ++i) row(sbeg + i);
    }
}

// ---------------------------------------------------------------------------
// K4: masked softmax over S per (b,h) row; writes attn output.
// grid 512 (= B*H), block 256.
__global__ __launch_bounds__(256) void k4_softmax(const float* __restrict__ energy,
                                                  const int* __restrict__ key_len,
                                                  float* __restrict__ attn) {
    const int bh = blockIdx.x;  // b*H + h
    const int b = bh >> 3;
    const int t = threadIdx.x;

    const int klen = key_len[b];
    const float* e = energy + (size_t)bh * S_;
    float ev[8];
    float m = -3.0e38f;
#pragma unroll
    for (int j = 0; j < 8; ++j) {
        int s = t + j * 256;
        float x = (s < klen) ? e[s] : -3.0e38f;
        ev[j] = x;
        m = fmaxf(m, x);
    }
#pragma unroll
    for (int off = 32; off >= 1; off >>= 1) m = fmaxf(m, __shfl_xor(m, off, 64));
    __shared__ float redm[4];
    if ((t & 63) == 0) redm[t >> 6] = m;
    __syncthreads();
    m = fmaxf(fmaxf(redm[0], redm[1]), fmaxf(redm[2], redm[3]));

    float sum = 0.f;
#pragma unroll
    for (int j = 0; j < 8; ++j) {
        int s = t + j * 256;
        float p = (s < klen) ? __expf(ev[j] - m) : 0.f;
        ev[j] = p;
        sum += p;
    }
#pragma unroll
    for (int off = 32; off >= 1; off >>= 1) sum += __shfl_xor(sum, off, 64);
    __shared__ float reds[4];
    if ((t & 63) == 0) reds[t >> 6] = sum;
    __syncthreads();
    sum = reds[0] + reds[1] + reds[2] + reds[3];
    const float inv = 1.f / sum;

    float* a = attn + (size_t)bh * S_;
#pragma unroll
    for (int j = 0; j < 8; ++j) a[t + j * 256] = ev[j] * inv;  // masked -> exact 0
}

// ---------------------------------------------------------------------------
// K5: partial context per 64-row chunk p: part[p][b][h][d] = sum_{s in chunk}
// attn[b,h,s]*value[b,s,d]. grid (16 s-chunks of 128, 64 b), block 256 =
// 128 float4-cols x 2 s-halves. No atomics.
__global__ __launch_bounds__(256) void k5_context(const float* __restrict__ value,
                                                  const float* __restrict__ attn,
                                                  const int* __restrict__ key_len,
                                                  float* __restrict__ part) {
    const int b = blockIdx.y;
    const int klen = key_len[b];
    const int s_base = blockIdx.x * 128;
    if (s_base >= klen) return;  // attn is exactly 0 there
    const int t = threadIdx.x;

    __shared__ float at[8][128];
#pragma unroll
    for (int i = 0; i < 4; ++i) {
        int idx = t + i * 256, h = idx >> 7, si = idx & 127;
        int s = s_base + si;
        at[h][si] = (s < klen) ? attn[((size_t)b * H_ + h) * S_ + s] : 0.f;
    }
    __syncthreads();

    const int col = t & 127;   // float4 column index
    const int sh = t >> 7;     // s-half 0/1 (64 rows each)
    const int d = col * 4;
    const int base_si = sh * 64;
    const int valid = min(64, klen - s_base - base_si);
    if (valid <= 0) return;  // this partial chunk is excluded by K6

    float4 acc[8];
#pragma unroll
    for (int h = 0; h < H_; ++h) acc[h] = make_float4(0.f, 0.f, 0.f, 0.f);

    auto step = [&](int si) {
        const float4 v = *reinterpret_cast<const float4*>(
            value + (size_t)(b * S_ + s_base + base_si + si) * KD_ + d);
#pragma unroll
        for (int h = 0; h < H_; ++h) {
            const float a = at[h][base_si + si];
            acc[h].x += a * v.x; acc[h].y += a * v.y;
            acc[h].z += a * v.z; acc[h].w += a * v.w;
        }
    };
    if (valid == 64) {
#pragma unroll 4
        for (int si = 0; si < 64; ++si) step(si);
    } else {
        for (int si = 0; si < valid; ++si) step(si);
    }

    const int p = blockIdx.x * 2 + sh;  // 64-row chunk index
    float* pp = part + (((size_t)p * B_ + b) * H_) * KD_;
#pragma unroll
    for (int h = 0; h < H_; ++h)
        *reinterpret_cast<float4*>(pp + h * KD_ + d) = acc[h];
}

// ---------------------------------------------------------------------------
// K6: ctx[b,h,d] = sum_{p < ceil(klen/64)} part[p][b][h][d]
// grid 256, block 256: one float4 per thread (65536 total).
__global__ __launch_bounds__(256) void k6_reduce(const float* __restrict__ part,
                                                 const int* __restrict__ key_len,
                                                 float* __restrict__ ctx) {
    const int g = blockIdx.x * 256 + threadIdx.x;  // float4 index
    const int d4 = g & 127;
    const int h = (g >> 7) & 7;
    const int b = g >> 10;
    const int nc = (key_len[b] + 63) >> 6;  // live chunks; only these were written
    float4 s = make_float4(0.f, 0.f, 0.f, 0.f);
    for (int p = 0; p < nc; ++p) {
        const float4 v = *reinterpret_cast<const float4*>(
            part + (((size_t)p * B_ + b) * H_ + h) * KD_ + d4 * 4);
        s.x += v.x; s.y += v.y; s.z += v.z; s.w += v.w;
    }
    *reinterpret_cast<float4*>(ctx + ((size_t)b * H_ + h) * KD_ + d4 * 4) = s;
}

// ---------------------------------------------------------------------------
extern "C" void kernel_launch(void* const* d_in, const int* in_sizes, int n_in,
                              void* d_out, int out_size, void* d_ws, size_t ws_size,
                              hipStream_t stream) {
    const float* query   = (const float*)d_in[0];  // (B, QD)
    const float* keys    = (const float*)d_in[1];  // (B, S, KD)
    const float* value   = (const float*)d_in[2];  // (B, S, KD)
    const int*   key_len = (const int*)d_in[3];    // (B,)
    const float* Wq      = (const float*)d_in[4];  // (H, AD, QD)
    const float* Wk      = (const float*)d_in[5];  // (H, AD, KD)

    float* out = (float*)d_out;
    float* ctx_out  = out;                          // (B, H*KD) = 262144 floats
    float* attn_out = out + (size_t)B_ * H_ * KD_;  // (B, H, S) = 1048576 floats

    float* ws      = (float*)d_ws;
    float* q_ws    = ws;                                   // B*H*AD = 262144
    float* qk_ws   = ws + (size_t)B_ * H_ * AD_;           // B*H*KD = 262144
    float* e_ws    = qk_ws + (size_t)B_ * H_ * KD_;        // B*H*S  = 1048576
    float* part_ws = e_ws + (size_t)B_ * H_ * S_;          // 32*B*H*KD = 8388608

    hipLaunchKernelGGL(k1_qproj, dim3(4, 64), dim3(256), 0, stream, query, Wq, q_ws);
    hipLaunchKernelGGL(k2_qk, dim3(4, 8, 8), dim3(256), 0, stream, q_ws, Wk, qk_ws);
    hipLaunchKernelGGL(k3_energy, dim3(32, 64), dim3(256), 0, stream,
                       keys, qk_ws, key_len, e_ws);
    hipLaunchKernelGGL(k4_softmax, dim3(512), dim3(256), 0, stream,
                       e_ws, key_len, attn_out);
    hipLaunchKernelGGL(k5_context, dim3(16, 64), dim3(256), 0, stream,
                       value, attn_out, key_len, part_ws);
    hipLaunchKernelGGL(k6_reduce, dim3(256), dim3(256), 0, stream,
                       part_ws, key_len, ctx_out);
}